// Round 15
// baseline (156.495 us; speedup 1.0000x reference)
//
#include <hip/hip_runtime.h>
#include <math.h>

#define D   128
#define HP  32
#define WP  32
#define M   64
#define Bb  8
#define Tt  16
#define P   (HP*WP)      // 1024
#define BT  (Bb*Tt)      // 128
#define EPSF 1e-5f
#define SCALE 0.08838834764831845f   // 1/sqrt(128)

typedef __attribute__((ext_vector_type(8))) _Float16 half8;
typedef __attribute__((ext_vector_type(8))) short    short8;
typedef __attribute__((ext_vector_type(4))) float    floatx4;

// ---------------------------------------------------------------------------
// Prep: RoPE cos/sin table + Wq/Wk fp32->fp16.  (validated)
// ---------------------------------------------------------------------------
__global__ __launch_bounds__(1024)
void prep(const float* __restrict__ Wq, const float* __restrict__ Wk,
          _Float16* __restrict__ W16q, _Float16* __restrict__ W16k,
          float2* __restrict__ ropetab)
{
  const int b = blockIdx.x, t = threadIdx.x;
  if (b == 0) {
    const int gq = t >> 5, coord = t & 31;
    const float theta = __powf(100.0f, -4.0f*(float)(gq+1)/128.0f);
    float s, c;
    __sincosf(theta*(float)coord, &s, &c);
    ropetab[t] = make_float2(c, s);
  } else if (b <= 16) {
    const int i = (b-1)*1024 + t;
    W16q[i] = (_Float16)Wq[i];
  } else {
    const int i = (b-17)*1024 + t;
    W16k[i] = (_Float16)Wk[i];
  }
}

// ---------------------------------------------------------------------------
// Projection + RoPE + LayerNorm (R10 fused kernel, validated twice).
// K-path also emits V^T via LDS re-stage into the dead W space.
// ---------------------------------------------------------------------------
template<bool IS_Q>
__global__ __launch_bounds__(256)
void proj_reg(const float* __restrict__ xin,
              const _Float16* __restrict__ W16,
              const float* __restrict__ bvec,
              const float* __restrict__ g,
              const float* __restrict__ bln,
              const int*   __restrict__ positions,
              const float2* __restrict__ ropetab,
              _Float16* __restrict__ yout,
              _Float16* __restrict__ vt)
{
  const int tid = threadIdx.x;
  const int w = tid >> 6, lane = tid & 63;
  const int gg = lane >> 4, c = lane & 15;
  const int block0 = blockIdx.x * 64;

  __shared__ _Float16 wl[128*128];

  {
    const short8* wg = (const short8*)W16;
    #pragma unroll
    for (int it = 0; it < 8; ++it) {
      const int idx = tid + 256*it;
      const int row = idx >> 4, col8 = idx & 15;
      const short8 v = wg[idx];
      const int byte = row*256 + col8*16;
      *(short8*)((char*)wl + (byte ^ ((row&7)<<4))) = v;
    }
  }
  __syncthreads();

  const float* xr = xin + (size_t)(block0 + w*16 + c) * D;
  half8 aq[4];
  #pragma unroll
  for (int ks = 0; ks < 4; ++ks) {
    const float4 f0 = *(const float4*)(xr + ks*32 + gg*8);
    const float4 f1 = *(const float4*)(xr + ks*32 + gg*8 + 4);
    _Float16 h[8] = {(_Float16)f0.x,(_Float16)f0.y,(_Float16)f0.z,(_Float16)f0.w,
                     (_Float16)f1.x,(_Float16)f1.y,(_Float16)f1.z,(_Float16)f1.w};
    aq[ks] = *(half8*)h;
  }

  floatx4 acc[8];
  #pragma unroll
  for (int jt = 0; jt < 8; ++jt) {
    floatx4 a4 = (floatx4){0.f,0.f,0.f,0.f};
    #pragma unroll
    for (int ks = 0; ks < 4; ++ks) {
      const int brow = jt*16 + c;
      const int byte = brow*256 + (gg*8 + ks*32)*2;
      const half8 bf = *(const half8*)((const char*)wl + (byte ^ ((brow&7)<<4)));
      a4 = __builtin_amdgcn_mfma_f32_16x16x32_f16(aq[ks], bf, a4, 0, 0, 0);
    }
    acc[jt] = a4;
  }

  if constexpr (!IS_Q) {
    __syncthreads();
    _Float16* xs = wl;
    {
      const float4* xg = (const float4*)(xin + (size_t)block0 * D);
      #pragma unroll
      for (int it = 0; it < 4; ++it) {
        const int idx = tid + 256*it;
        const int row = idx >> 4, col8 = idx & 15;
        const float4 f0 = xg[idx*2], f1 = xg[idx*2+1];
        _Float16 h[8] = {(_Float16)f0.x,(_Float16)f0.y,(_Float16)f0.z,(_Float16)f0.w,
                         (_Float16)f1.x,(_Float16)f1.y,(_Float16)f1.z,(_Float16)f1.w};
        const int byte = row*256 + col8*16;
        *(half8*)((char*)xs + (byte ^ ((row&7)<<4))) = *(half8*)h;
      }
    }
    __syncthreads();
    {
      const int bt2 = block0 >> 10;
      const int p0  = block0 & (P-1);
      const int dd  = tid & 127, ph2 = tid >> 7;
      short hv[32];
      #pragma unroll
      for (int i = 0; i < 32; ++i) {
        const int pl2 = ph2*32 + i;
        const int byte = pl2*256 + dd*2;
        hv[i] = *(const short*)((const char*)xs + (byte ^ ((pl2&7)<<4)));
      }
      short8* dst = (short8*)(vt + ((size_t)bt2*D + dd)*P + p0 + ph2*32);
      #pragma unroll
      for (int i = 0; i < 4; ++i) dst[i] = ((short8*)hv)[i];
    }
  }

  const int rr = c & 3;
  int coordv[4];
  #pragma unroll
  for (int r = 0; r < 4; ++r) {
    const int grow = block0 + w*16 + gg*4 + r;
    int hh, ww;
    if (IS_Q) { const int pos = positions[grow]; hh = pos >> 5; ww = pos & 31; }
    else      { const int p = grow & (P-1);      hh = p  >> 5; ww = p  & 31; }
    coordv[r] = (rr & 1) ? ww : hh;
  }

  float fin[8][4];
  float s1[4] = {0.f,0.f,0.f,0.f}, s2[4] = {0.f,0.f,0.f,0.f};
  #pragma unroll
  for (int jt = 0; jt < 8; ++jt) {
    const float bj = bvec[jt*16 + c];
    const int gq = jt*4 + (c >> 2);
    #pragma unroll
    for (int r = 0; r < 4; ++r) {
      const float val = acc[jt][r] + bj;
      const float2 tt = ropetab[gq*32 + coordv[r]];
      const float p2 = __shfl_xor(val, 2);
      const float f1v = (rr & 1) ? (val*tt.x + p2*tt.y)
                                 : (val*tt.x - p2*tt.y);
      const float g2 = __shfl_xor(f1v, 2);
      const float fn = (rr >= 2)
          ? ((rr & 1) ? (val*tt.x + g2*tt.y) : (val*tt.x - g2*tt.y))
          : f1v;
      fin[jt][r] = fn;
      s1[r] += fn;
      s2[r] += fn*fn;
    }
  }

  #pragma unroll
  for (int r = 0; r < 4; ++r) {
    #pragma unroll
    for (int off = 1; off <= 8; off <<= 1) {
      s1[r] += __shfl_xor(s1[r], off);
      s2[r] += __shfl_xor(s2[r], off);
    }
  }

  #pragma unroll
  for (int r = 0; r < 4; ++r) {
    const float mu   = s1[r] * (1.f/128.f);
    const float var  = s2[r] * (1.f/128.f) - mu*mu;
    const float rinv = rsqrtf(var + EPSF);
    const int grow = block0 + w*16 + gg*4 + r;
    _Float16* yo = yout + (size_t)grow * D;
    #pragma unroll
    for (int jt = 0; jt < 8; ++jt) {
      const int col = jt*16 + c;
      const float nv = (fin[jt][r] - mu) * rinv * g[col] + bln[col];
      yo[col] = (_Float16)nv;
    }
  }
}

// ---------------------------------------------------------------------------
// Flash attention, fixed-max softmax (m=4), race-safe (validated R13/R14).
// ---------------------------------------------------------------------------
__global__ __launch_bounds__(256)
void attn_mfma(const _Float16* __restrict__ q,
               const _Float16* __restrict__ k,
               const _Float16* __restrict__ vt,
               const int* __restrict__ positions,
               float* __restrict__ out)
{
  const int bt  = blockIdx.x & (BT-1);
  const int qq  = blockIdx.x >> 7;
  const int tid = threadIdx.x;
  const int w   = tid >> 6, lane = tid & 63;
  const int g   = lane >> 4, c = lane & 15;

  __shared__ _Float16 pl[4][16][88];
  __shared__ _Float16 o16[4][16][136];
  __shared__ float    l_lds[4][16];

  const _Float16* qrow = q + (size_t)(bt*M + qq*16 + c) * D + g*8;
  half8 aq[4];
  #pragma unroll
  for (int ks = 0; ks < 4; ++ks) aq[ks] = *(const half8*)(qrow + ks*32);

  float ph[4], pw[4];
  #pragma unroll
  for (int r = 0; r < 4; ++r) {
    const int pos = positions[bt*M + qq*16 + g*4 + r];
    ph[r] = (float)(pos >> 5); pw[r] = (float)(pos & 31);
  }

  float lsum[4] = {0.f, 0.f, 0.f, 0.f};
  floatx4 oacc[8];
  #pragma unroll
  for (int dt = 0; dt < 8; ++dt) oacc[dt] = (floatx4){0.f,0.f,0.f,0.f};

  const _Float16* kb = k  + ((size_t)bt * P) * D;
  const _Float16* vb = vt + ((size_t)bt * D) * P;

  for (int t = 0; t < 4; ++t) {
    const int p0 = w*256 + t*64;

    floatx4 s[4];
    #pragma unroll
    for (int pt = 0; pt < 4; ++pt) {
      floatx4 a4 = (floatx4){0.f,0.f,0.f,0.f};
      const _Float16* krow = kb + (size_t)(p0 + pt*16 + c) * D + g*8;
      #pragma unroll
      for (int ks = 0; ks < 4; ++ks)
        a4 = __builtin_amdgcn_mfma_f32_16x16x32_f16(
                 aq[ks], *(const half8*)(krow + ks*32), a4, 0, 0, 0);
      s[pt] = a4;
    }

    #pragma unroll
    for (int pt = 0; pt < 4; ++pt) {
      const int pp = p0 + pt*16 + c;
      const float hh = (float)(pp >> 5), ww = (float)(pp & 31);
      #pragma unroll
      for (int r = 0; r < 4; ++r) {
        const float dx = ph[r] - hh, dy = pw[r] - ww;
        const float sv = s[pt][r]*SCALE - 0.125f*sqrtf(dx*dx + dy*dy);
        const float e  = __expf(sv - 4.0f);
        const _Float16 eh = (_Float16)e;
        pl[w][g*4 + r][pt*16 + c] = eh;
        lsum[r] += (float)eh;
      }
    }

    #pragma unroll
    for (int ks = 0; ks < 2; ++ks) {
      const half8 pa = *(const half8*)(&pl[w][c][ks*32 + g*8]);
      #pragma unroll
      for (int dt = 0; dt < 8; ++dt) {
        const half8 bv = *(const half8*)(vb + (size_t)(dt*16 + c)*P
                                            + p0 + ks*32 + g*8);
        oacc[dt] = __builtin_amdgcn_mfma_f32_16x16x32_f16(pa, bv, oacc[dt], 0,0,0);
      }
    }
  }

  __syncthreads();

  #pragma unroll
  for (int r = 0; r < 4; ++r) {
    #pragma unroll
    for (int off = 1; off <= 8; off <<= 1)
      lsum[r] += __shfl_xor(lsum[r], off);
  }
  if (c == 0) {
    #pragma unroll
    for (int r = 0; r < 4; ++r) l_lds[w][g*4 + r] = lsum[r];
  }

  #pragma unroll
  for (int dt = 0; dt < 8; ++dt)
    #pragma unroll
    for (int r = 0; r < 4; ++r)
      o16[w][g*4 + r][dt*16 + c] = (_Float16)oacc[dt][r];
  __syncthreads();

  const int qi = tid >> 4, dg = tid & 15;
  const float L = l_lds[0][qi] + l_lds[1][qi] + l_lds[2][qi] + l_lds[3][qi];
  const float inv = 1.0f / L;
  float a2[8] = {0.f,0.f,0.f,0.f,0.f,0.f,0.f,0.f};
  #pragma unroll
  for (int w2 = 0; w2 < 4; ++w2) {
    const half8 ov = *(const half8*)(&o16[w2][qi][dg*8]);
    #pragma unroll
    for (int dd = 0; dd < 8; ++dd) a2[dd] += (float)ov[dd];
  }
  float* orow = out + (size_t)(bt*M + qq*16 + qi) * D + dg*8;
  #pragma unroll
  for (int dd = 0; dd < 8; ++dd) orow[dd] = a2[dd] * inv;
}

// ===========================================================================
// ABLATION PROBES (write only to dead scratch; run after the real pipeline).
// ===========================================================================

// P1: W-stage + MFMA + RoPE/LN compute; checksum store (no kout/vt stores).
__global__ __launch_bounds__(256)
void probe_gemm(const float* __restrict__ xin,
                const _Float16* __restrict__ W16,
                const float* __restrict__ bvec,
                const float* __restrict__ g,
                const float* __restrict__ bln,
                const float2* __restrict__ ropetab,
                float* __restrict__ chk_out)
{
  const int tid = threadIdx.x;
  const int w = tid >> 6, lane = tid & 63;
  const int gg = lane >> 4, c = lane & 15;
  const int block0 = blockIdx.x * 64;

  __shared__ _Float16 wl[128*128];
  {
    const short8* wg = (const short8*)W16;
    #pragma unroll
    for (int it = 0; it < 8; ++it) {
      const int idx = tid + 256*it;
      const int row = idx >> 4, col8 = idx & 15;
      const short8 v = wg[idx];
      const int byte = row*256 + col8*16;
      *(short8*)((char*)wl + (byte ^ ((row&7)<<4))) = v;
    }
  }
  __syncthreads();

  const float* xr = xin + (size_t)(block0 + w*16 + c) * D;
  half8 aq[4];
  #pragma unroll
  for (int ks = 0; ks < 4; ++ks) {
    const float4 f0 = *(const float4*)(xr + ks*32 + gg*8);
    const float4 f1 = *(const float4*)(xr + ks*32 + gg*8 + 4);
    _Float16 h[8] = {(_Float16)f0.x,(_Float16)f0.y,(_Float16)f0.z,(_Float16)f0.w,
                     (_Float16)f1.x,(_Float16)f1.y,(_Float16)f1.z,(_Float16)f1.w};
    aq[ks] = *(half8*)h;
  }

  floatx4 acc[8];
  #pragma unroll
  for (int jt = 0; jt < 8; ++jt) {
    floatx4 a4 = (floatx4){0.f,0.f,0.f,0.f};
    #pragma unroll
    for (int ks = 0; ks < 4; ++ks) {
      const int brow = jt*16 + c;
      const int byte = brow*256 + (gg*8 + ks*32)*2;
      const half8 bf = *(const half8*)((const char*)wl + (byte ^ ((brow&7)<<4)));
      a4 = __builtin_amdgcn_mfma_f32_16x16x32_f16(aq[ks], bf, a4, 0, 0, 0);
    }
    acc[jt] = a4;
  }

  const int rr = c & 3;
  int coordv[4];
  #pragma unroll
  for (int r = 0; r < 4; ++r) {
    const int grow = block0 + w*16 + gg*4 + r;
    const int p = grow & (P-1);
    coordv[r] = (rr & 1) ? (p & 31) : (p >> 5);
  }

  float fin[8][4];
  float s1[4] = {0.f,0.f,0.f,0.f}, s2[4] = {0.f,0.f,0.f,0.f};
  #pragma unroll
  for (int jt = 0; jt < 8; ++jt) {
    const float bj = bvec[jt*16 + c];
    const int gq = jt*4 + (c >> 2);
    #pragma unroll
    for (int r = 0; r < 4; ++r) {
      const float val = acc[jt][r] + bj;
      const float2 tt = ropetab[gq*32 + coordv[r]];
      const float p2 = __shfl_xor(val, 2);
      const float f1v = (rr & 1) ? (val*tt.x + p2*tt.y)
                                 : (val*tt.x - p2*tt.y);
      const float g2 = __shfl_xor(f1v, 2);
      const float fn = (rr >= 2)
          ? ((rr & 1) ? (val*tt.x + g2*tt.y) : (val*tt.x - g2*tt.y))
          : f1v;
      fin[jt][r] = fn;
      s1[r] += fn;
      s2[r] += fn*fn;
    }
  }

  float chk = 0.f;
  #pragma unroll
  for (int r = 0; r < 4; ++r) {
    #pragma unroll
    for (int off = 1; off <= 8; off <<= 1) {
      s1[r] += __shfl_xor(s1[r], off);
      s2[r] += __shfl_xor(s2[r], off);
    }
    const float mu   = s1[r] * (1.f/128.f);
    const float var  = s2[r] * (1.f/128.f) - mu*mu;
    const float rinv = rsqrtf(var + EPSF);
    #pragma unroll
    for (int jt = 0; jt < 8; ++jt) {
      const int col = jt*16 + c;
      chk += (fin[jt][r] - mu) * rinv * g[col] + bln[col];
    }
  }
  chk_out[(size_t)blockIdx.x*256 + tid] = chk;   // coalesced 2MB
}

// P2: store patterns only (kout scalar shorts + vt short8), no loads/LDS.
__global__ __launch_bounds__(256)
void probe_stores(_Float16* __restrict__ sk, _Float16* __restrict__ svt)
{
  const int tid = threadIdx.x;
  const int w = tid >> 6, lane = tid & 63;
  const int gg = lane >> 4, c = lane & 15;
  const int block0 = blockIdx.x * 64;
  const _Float16 hv = (_Float16)(float)(tid & 7);

  #pragma unroll
  for (int r = 0; r < 4; ++r) {
    const int grow = block0 + w*16 + gg*4 + r;
    _Float16* yo = sk + (size_t)grow * D;
    #pragma unroll
    for (int jt = 0; jt < 8; ++jt) yo[jt*16 + c] = hv;
  }

  const int bt2 = block0 >> 10;
  const int p0  = block0 & (P-1);
  const int dd  = tid & 127, ph2 = tid >> 7;
  short8 sv;
  #pragma unroll
  for (int i = 0; i < 8; ++i) sv[i] = (short)(tid + i);
  short8* dst = (short8*)(svt + ((size_t)bt2*D + dd)*P + p0 + ph2*32);
  #pragma unroll
  for (int i = 0; i < 4; ++i) dst[i] = sv;
}

// P3: global read patterns only (A-frags + V-tile), checksum store.
__global__ __launch_bounds__(256)
void probe_loads(const float* __restrict__ mv, float* __restrict__ chk_out)
{
  const int tid = threadIdx.x;
  const int w = tid >> 6, lane = tid & 63;
  const int gg = lane >> 4, c = lane & 15;
  const int block0 = blockIdx.x * 64;

  float chk = 0.f;
  const float* xr = mv + (size_t)(block0 + w*16 + c) * D;
  #pragma unroll
  for (int ks = 0; ks < 4; ++ks) {
    const float4 f0 = *(const float4*)(xr + ks*32 + gg*8);
    const float4 f1 = *(const float4*)(xr + ks*32 + gg*8 + 4);
    chk += f0.x+f0.y+f0.z+f0.w + f1.x+f1.y+f1.z+f1.w;
  }
  const float4* xg = (const float4*)(mv + (size_t)block0 * D);
  #pragma unroll
  for (int it = 0; it < 4; ++it) {
    const int idx = tid + 256*it;
    const float4 a = xg[idx*2], b = xg[idx*2+1];
    chk += a.x+a.y+a.z+a.w + b.x+b.y+b.z+b.w;
  }
  chk_out[(size_t)blockIdx.x*256 + tid] = chk;
}

// ---------------------------------------------------------------------------
extern "C" void kernel_launch(void* const* d_in, const int* in_sizes, int n_in,
                              void* d_out, int out_size, void* d_ws, size_t ws_size,
                              hipStream_t stream) {
  const float* t    = (const float*)d_in[0];
  const float* mv   = (const float*)d_in[1];
  const int*   pos  = (const int*)  d_in[2];
  const float* Wq   = (const float*)d_in[3];
  const float* bq   = (const float*)d_in[4];
  const float* Wk   = (const float*)d_in[5];
  const float* bk   = (const float*)d_in[6];
  const float* ln_g = (const float*)d_in[7];
  const float* ln_b = (const float*)d_in[8];
  float* out = (float*)d_out;

  _Float16* qbuf = (_Float16*)d_ws;                 // 2 MB
  _Float16* kbuf = qbuf + (size_t)BT*M*D;           // 32 MB
  _Float16* vtbf = kbuf + (size_t)BT*P*D;           // 32 MB
  _Float16* w16q = vtbf + (size_t)BT*P*D;
  _Float16* w16k = w16q + D*D;
  float2*   rtab = (float2*)(w16k + D*D);

  // probe scratch at +100 MiB (d_ws is 256 MiB; pipeline uses < 70 MiB)
  char* probe_base = (char*)d_ws + (size_t)100*1024*1024;
  float*    chk1 = (float*)probe_base;                         // 2 MB
  float*    chk3 = chk1 + (size_t)2048*256;                    // 2 MB
  _Float16* sk   = (_Float16*)(chk3 + (size_t)2048*256);       // 32 MB
  _Float16* svt  = sk + (size_t)BT*P*D;                        // 32 MB

  prep<<<33, 1024, 0, stream>>>(Wq, Wk, w16q, w16k, rtab);
  proj_reg<false><<<BT*P/64, 256, 0, stream>>>(mv, w16k, bk, ln_g, ln_b, nullptr,
                                               rtab, kbuf, vtbf);
  proj_reg<true ><<<BT*M/64, 256, 0, stream>>>(t,  w16q, bq, ln_g, ln_b, pos,
                                               rtab, qbuf, nullptr);
  attn_mfma<<<512, 256, 0, stream>>>(qbuf, kbuf, vtbf, pos, out);

  // --- ablation probes (scratch only; after real pipeline) ---
  probe_gemm  <<<BT*P/64, 256, 0, stream>>>(mv, w16k, bk, ln_g, ln_b, rtab, chk1);
  probe_stores<<<BT*P/64, 256, 0, stream>>>(sk, svt);
  probe_loads <<<BT*P/64, 256, 0, stream>>>(mv, chk3);
}

// Round 16
// 113.405 us; speedup vs baseline: 1.3800x; 1.3800x over previous
//
#include <hip/hip_runtime.h>
#include <math.h>

#define D   128
#define HP  32
#define WP  32
#define M   64
#define Bb  8
#define Tt  16
#define P   (HP*WP)      // 1024
#define BT  (Bb*Tt)      // 128
#define EPSF 1e-5f
#define SCALE 0.08838834764831845f   // 1/sqrt(128)

typedef __attribute__((ext_vector_type(8))) _Float16 half8;
typedef __attribute__((ext_vector_type(8))) short    short8;
typedef __attribute__((ext_vector_type(4))) float    floatx4;

// ---------------------------------------------------------------------------
// Prep: RoPE cos/sin table + Wq/Wk fp32->fp16.  (validated)
// ---------------------------------------------------------------------------
__global__ __launch_bounds__(1024)
void prep(const float* __restrict__ Wq, const float* __restrict__ Wk,
          _Float16* __restrict__ W16q, _Float16* __restrict__ W16k,
          float2* __restrict__ ropetab)
{
  const int b = blockIdx.x, t = threadIdx.x;
  if (b == 0) {
    const int gq = t >> 5, coord = t & 31;
    const float theta = __powf(100.0f, -4.0f*(float)(gq+1)/128.0f);
    float s, c;
    __sincosf(theta*(float)coord, &s, &c);
    ropetab[t] = make_float2(c, s);
  } else if (b <= 16) {
    const int i = (b-1)*1024 + t;
    W16q[i] = (_Float16)Wq[i];
  } else {
    const int i = (b-17)*1024 + t;
    W16k[i] = (_Float16)Wk[i];
  }
}

// ---------------------------------------------------------------------------
// Projection + RoPE + LayerNorm.  R10 fused structure; NEW in R16: the final
// fp16 Y values bounce through the (dead) wl LDS with R3's validated
// pair-pack layout (stride 136), so kout stores are 4x half8 per thread
// instead of 32 scalar 2-byte stores (8x fewer VMEM store instructions).
// K-path also emits V^T via LDS re-stage into the dead W space (validated).
// ---------------------------------------------------------------------------
template<bool IS_Q>
__global__ __launch_bounds__(256)
void proj_reg(const float* __restrict__ xin,
              const _Float16* __restrict__ W16,
              const float* __restrict__ bvec,
              const float* __restrict__ g,
              const float* __restrict__ bln,
              const int*   __restrict__ positions,
              const float2* __restrict__ ropetab,
              _Float16* __restrict__ yout,
              _Float16* __restrict__ vt)
{
  const int tid = threadIdx.x;
  const int w = tid >> 6, lane = tid & 63;
  const int gg = lane >> 4, c = lane & 15;
  const int block0 = blockIdx.x * 64;

  __shared__ _Float16 wl[128*128];   // W (32KB); reused for V tile, then Y tile

  // ---- stage W (validated) ----
  {
    const short8* wg = (const short8*)W16;
    #pragma unroll
    for (int it = 0; it < 8; ++it) {
      const int idx = tid + 256*it;
      const int row = idx >> 4, col8 = idx & 15;
      const short8 v = wg[idx];
      const int byte = row*256 + col8*16;
      *(short8*)((char*)wl + (byte ^ ((row&7)<<4))) = v;
    }
  }
  __syncthreads();

  // ---- A fragments: global fp32 -> fp16 regs (validated) ----
  const float* xr = xin + (size_t)(block0 + w*16 + c) * D;
  half8 aq[4];
  #pragma unroll
  for (int ks = 0; ks < 4; ++ks) {
    const float4 f0 = *(const float4*)(xr + ks*32 + gg*8);
    const float4 f1 = *(const float4*)(xr + ks*32 + gg*8 + 4);
    _Float16 h[8] = {(_Float16)f0.x,(_Float16)f0.y,(_Float16)f0.z,(_Float16)f0.w,
                     (_Float16)f1.x,(_Float16)f1.y,(_Float16)f1.z,(_Float16)f1.w};
    aq[ks] = *(half8*)h;
  }

  // ---- MFMA (validated) ----
  floatx4 acc[8];
  #pragma unroll
  for (int jt = 0; jt < 8; ++jt) {
    floatx4 a4 = (floatx4){0.f,0.f,0.f,0.f};
    #pragma unroll
    for (int ks = 0; ks < 4; ++ks) {
      const int brow = jt*16 + c;
      const int byte = brow*256 + (gg*8 + ks*32)*2;
      const half8 bf = *(const half8*)((const char*)wl + (byte ^ ((brow&7)<<4)));
      a4 = __builtin_amdgcn_mfma_f32_16x16x32_f16(aq[ks], bf, a4, 0, 0, 0);
    }
    acc[jt] = a4;
  }

  // ---- K path: V^T emit via LDS re-stage into dead wl (validated) ----
  if constexpr (!IS_Q) {
    __syncthreads();   // all waves done reading W from wl
    _Float16* xs = wl;
    {
      const float4* xg = (const float4*)(xin + (size_t)block0 * D);
      #pragma unroll
      for (int it = 0; it < 4; ++it) {
        const int idx = tid + 256*it;
        const int row = idx >> 4, col8 = idx & 15;
        const float4 f0 = xg[idx*2], f1 = xg[idx*2+1];
        _Float16 h[8] = {(_Float16)f0.x,(_Float16)f0.y,(_Float16)f0.z,(_Float16)f0.w,
                         (_Float16)f1.x,(_Float16)f1.y,(_Float16)f1.z,(_Float16)f1.w};
        const int byte = row*256 + col8*16;
        *(half8*)((char*)xs + (byte ^ ((row&7)<<4))) = *(half8*)h;
      }
    }
    __syncthreads();
    {
      const int bt2 = block0 >> 10;
      const int p0  = block0 & (P-1);
      const int dd  = tid & 127, ph2 = tid >> 7;
      short hv[32];
      #pragma unroll
      for (int i = 0; i < 32; ++i) {
        const int pl2 = ph2*32 + i;
        const int byte = pl2*256 + dd*2;
        hv[i] = *(const short*)((const char*)xs + (byte ^ ((pl2&7)<<4)));
      }
      short8* dst = (short8*)(vt + ((size_t)bt2*D + dd)*P + p0 + ph2*32);
      #pragma unroll
      for (int i = 0; i < 4; ++i) dst[i] = ((short8*)hv)[i];
    }
  }

  // ---- bias + RoPE + LN in registers (validated R8 math) ----
  const int rr = c & 3;
  int coordv[4];
  #pragma unroll
  for (int r = 0; r < 4; ++r) {
    const int grow = block0 + w*16 + gg*4 + r;
    int hh, ww;
    if (IS_Q) { const int pos = positions[grow]; hh = pos >> 5; ww = pos & 31; }
    else      { const int p = grow & (P-1);      hh = p  >> 5; ww = p  & 31; }
    coordv[r] = (rr & 1) ? ww : hh;
  }

  float fin[8][4];
  float s1[4] = {0.f,0.f,0.f,0.f}, s2[4] = {0.f,0.f,0.f,0.f};
  #pragma unroll
  for (int jt = 0; jt < 8; ++jt) {
    const float bj = bvec[jt*16 + c];
    const int gq = jt*4 + (c >> 2);
    #pragma unroll
    for (int r = 0; r < 4; ++r) {
      const float val = acc[jt][r] + bj;
      const float2 tt = ropetab[gq*32 + coordv[r]];
      const float p2 = __shfl_xor(val, 2);
      const float f1v = (rr & 1) ? (val*tt.x + p2*tt.y)
                                 : (val*tt.x - p2*tt.y);
      const float g2 = __shfl_xor(f1v, 2);
      const float fn = (rr >= 2)
          ? ((rr & 1) ? (val*tt.x + g2*tt.y) : (val*tt.x - g2*tt.y))
          : f1v;
      fin[jt][r] = fn;
      s1[r] += fn;
      s2[r] += fn*fn;
    }
  }

  #pragma unroll
  for (int r = 0; r < 4; ++r) {
    #pragma unroll
    for (int off = 1; off <= 8; off <<= 1) {
      s1[r] += __shfl_xor(s1[r], off);
      s2[r] += __shfl_xor(s2[r], off);
    }
  }

  // ---- NEW: write final fp16 Y into dead wl (R3 pair-pack, stride 136) ----
  __syncthreads();   // wl fully dead (W reads / V^T emit reads complete)
  #pragma unroll
  for (int r = 0; r < 4; ++r) {
    const float mu   = s1[r] * (1.f/128.f);
    const float var  = s2[r] * (1.f/128.f) - mu*mu;
    const float rinv = rsqrtf(var + EPSF);
    const int row = w*16 + gg*4 + r;
    #pragma unroll
    for (int jt = 0; jt < 8; ++jt) {
      const int col = jt*16 + c;
      const float nv  = (fin[jt][r] - mu) * rinv * g[col] + bln[col];
      const float nvp = __shfl_xor(nv, 1);
      if ((c & 1) == 0) {
        const unsigned lo = (unsigned)__builtin_bit_cast(unsigned short, (_Float16)nv);
        const unsigned hi = (unsigned)__builtin_bit_cast(unsigned short, (_Float16)nvp);
        *(unsigned*)((char*)wl + row*272 + col*2) = lo | (hi << 16);
      }
    }
  }
  __syncthreads();

  // ---- vectorized kout store (R3 readback): 4x half8 per thread ----
  {
    const int row2 = tid >> 2;
    const int cb   = (tid & 3) * 32;
    half8* yo = (half8*)(yout + (size_t)(block0 + row2) * D + cb);
    #pragma unroll
    for (int i = 0; i < 4; ++i)
      yo[i] = *(const half8*)((const char*)wl + row2*272 + (cb + i*8)*2);
  }
}

// ---------------------------------------------------------------------------
// Flash attention, fixed-max softmax (m=4), race-safe (validated R13/R14).
// Bound proof (R9): P = exp(s-4) in [2.2e-7, 1500], fp16-safe, lsum > 0.
// ---------------------------------------------------------------------------
__global__ __launch_bounds__(256)
void attn_mfma(const _Float16* __restrict__ q,
               const _Float16* __restrict__ k,
               const _Float16* __restrict__ vt,
               const int* __restrict__ positions,
               float* __restrict__ out)
{
  const int bt  = blockIdx.x & (BT-1);
  const int qq  = blockIdx.x >> 7;
  const int tid = threadIdx.x;
  const int w   = tid >> 6, lane = tid & 63;
  const int g   = lane >> 4, c = lane & 15;

  __shared__ _Float16 pl[4][16][88];
  __shared__ _Float16 o16[4][16][136];
  __shared__ float    l_lds[4][16];

  const _Float16* qrow = q + (size_t)(bt*M + qq*16 + c) * D + g*8;
  half8 aq[4];
  #pragma unroll
  for (int ks = 0; ks < 4; ++ks) aq[ks] = *(const half8*)(qrow + ks*32);

  float ph[4], pw[4];
  #pragma unroll
  for (int r = 0; r < 4; ++r) {
    const int pos = positions[bt*M + qq*16 + g*4 + r];
    ph[r] = (float)(pos >> 5); pw[r] = (float)(pos & 31);
  }

  float lsum[4] = {0.f, 0.f, 0.f, 0.f};
  floatx4 oacc[8];
  #pragma unroll
  for (int dt = 0; dt < 8; ++dt) oacc[dt] = (floatx4){0.f,0.f,0.f,0.f};

  const _Float16* kb = k  + ((size_t)bt * P) * D;
  const _Float16* vb = vt + ((size_t)bt * D) * P;

  for (int t = 0; t < 4; ++t) {
    const int p0 = w*256 + t*64;

    floatx4 s[4];
    #pragma unroll
    for (int pt = 0; pt < 4; ++pt) {
      floatx4 a4 = (floatx4){0.f,0.f,0.f,0.f};
      const _Float16* krow = kb + (size_t)(p0 + pt*16 + c) * D + g*8;
      #pragma unroll
      for (int ks = 0; ks < 4; ++ks)
        a4 = __builtin_amdgcn_mfma_f32_16x16x32_f16(
                 aq[ks], *(const half8*)(krow + ks*32), a4, 0, 0, 0);
      s[pt] = a4;
    }

    #pragma unroll
    for (int pt = 0; pt < 4; ++pt) {
      const int pp = p0 + pt*16 + c;
      const float hh = (float)(pp >> 5), ww = (float)(pp & 31);
      #pragma unroll
      for (int r = 0; r < 4; ++r) {
        const float dx = ph[r] - hh, dy = pw[r] - ww;
        const float sv = s[pt][r]*SCALE - 0.125f*sqrtf(dx*dx + dy*dy);
        const float e  = __expf(sv - 4.0f);
        const _Float16 eh = (_Float16)e;
        pl[w][g*4 + r][pt*16 + c] = eh;
        lsum[r] += (float)eh;
      }
    }

    #pragma unroll
    for (int ks = 0; ks < 2; ++ks) {
      const half8 pa = *(const half8*)(&pl[w][c][ks*32 + g*8]);
      #pragma unroll
      for (int dt = 0; dt < 8; ++dt) {
        const half8 bv = *(const half8*)(vb + (size_t)(dt*16 + c)*P
                                            + p0 + ks*32 + g*8);
        oacc[dt] = __builtin_amdgcn_mfma_f32_16x16x32_f16(pa, bv, oacc[dt], 0,0,0);
      }
    }
  }

  __syncthreads();   // race fix: all waves' pl reads complete before epilogue

  #pragma unroll
  for (int r = 0; r < 4; ++r) {
    #pragma unroll
    for (int off = 1; off <= 8; off <<= 1)
      lsum[r] += __shfl_xor(lsum[r], off);
  }
  if (c == 0) {
    #pragma unroll
    for (int r = 0; r < 4; ++r) l_lds[w][g*4 + r] = lsum[r];
  }

  #pragma unroll
  for (int dt = 0; dt < 8; ++dt)
    #pragma unroll
    for (int r = 0; r < 4; ++r)
      o16[w][g*4 + r][dt*16 + c] = (_Float16)oacc[dt][r];
  __syncthreads();

  const int qi = tid >> 4, dg = tid & 15;
  const float L = l_lds[0][qi] + l_lds[1][qi] + l_lds[2][qi] + l_lds[3][qi];
  const float inv = 1.0f / L;
  float a2[8] = {0.f,0.f,0.f,0.f,0.f,0.f,0.f,0.f};
  #pragma unroll
  for (int w2 = 0; w2 < 4; ++w2) {
    const half8 ov = *(const half8*)(&o16[w2][qi][dg*8]);
    #pragma unroll
    for (int dd = 0; dd < 8; ++dd) a2[dd] += (float)ov[dd];
  }
  float* orow = out + (size_t)(bt*M + qq*16 + qi) * D + dg*8;
  #pragma unroll
  for (int dd = 0; dd < 8; ++dd) orow[dd] = a2[dd] * inv;
}

// ---------------------------------------------------------------------------
extern "C" void kernel_launch(void* const* d_in, const int* in_sizes, int n_in,
                              void* d_out, int out_size, void* d_ws, size_t ws_size,
                              hipStream_t stream) {
  const float* t    = (const float*)d_in[0];
  const float* mv   = (const float*)d_in[1];
  const int*   pos  = (const int*)  d_in[2];
  const float* Wq   = (const float*)d_in[3];
  const float* bq   = (const float*)d_in[4];
  const float* Wk   = (const float*)d_in[5];
  const float* bk   = (const float*)d_in[6];
  const float* ln_g = (const float*)d_in[7];
  const float* ln_b = (const float*)d_in[8];
  float* out = (float*)d_out;

  _Float16* qbuf = (_Float16*)d_ws;                 // 1,048,576 halfs
  _Float16* kbuf = qbuf + (size_t)BT*M*D;           // 16,777,216
  _Float16* vtbf = kbuf + (size_t)BT*P*D;           // 16,777,216
  _Float16* w16q = vtbf + (size_t)BT*P*D;           // 16,384
  _Float16* w16k = w16q + D*D;                      // 16,384
  float2*   rtab = (float2*)(w16k + D*D);           // 1,024 float2

  prep<<<33, 1024, 0, stream>>>(Wq, Wk, w16q, w16k, rtab);
  proj_reg<false><<<BT*P/64, 256, 0, stream>>>(mv, w16k, bk, ln_g, ln_b, nullptr,
                                               rtab, kbuf, vtbf);
  proj_reg<true ><<<BT*M/64, 256, 0, stream>>>(t,  w16q, bq, ln_g, ln_b, pos,
                                               rtab, qbuf, nullptr);
  attn_mfma<<<512, 256, 0, stream>>>(qbuf, kbuf, vtbf, pos, out);
}